// Round 14
// baseline (1002.087 us; speedup 1.0000x reference)
//
#include <hip/hip_runtime.h>
#include <hip/hip_bf16.h>

#define HEADS 8
#define DIM 512
#define HID 1024
#define NTOK 197
#define NPATCH 196
#define BATCH 64
#define MTOK (BATCH*NTOK)     // 12608
#define MPATCH (BATCH*NPATCH) // 12544
#define KPATCH 768

typedef __attribute__((ext_vector_type(8))) short vbf8;
typedef __attribute__((ext_vector_type(4))) float vf4;

__device__ inline float bf2f(short u) {
  union { unsigned int i; float f; } v; v.i = ((unsigned int)(unsigned short)u) << 16; return v.f;
}
__device__ inline short f2bf(float f) {
  union { float f; unsigned int i; } u; u.f = f;
  unsigned int r = u.i + 0x7fffu + ((u.i >> 16) & 1u);
  return (short)(r >> 16);
}

__device__ inline void gl_lds16(const void* g, void* l) {
  __builtin_amdgcn_global_load_lds(
      (const __attribute__((address_space(1))) void*)g,
      (__attribute__((address_space(3))) void*)l, 16, 0, 0);
}

// ---------------- weight convert + transpose: in[K][N] f32 -> out[N][K] bf16 ----
__global__ void k_cvt_t(const float* __restrict__ in, short* __restrict__ out, int K, int N) {
  int slice = blockIdx.z;
  in  += (size_t)slice * K * N;
  out += (size_t)slice * K * N;
  __shared__ short tile[64][72];
  int t = threadIdx.x;
  int k0 = blockIdx.y * 64, n0 = blockIdx.x * 64;
  int r = t >> 2, c4 = (t & 3) << 4;
  #pragma unroll
  for (int j = 0; j < 16; j += 4) {
    float4 v = *(const float4*)(in + (size_t)(k0 + r) * N + n0 + c4 + j);
    tile[r][c4 + j + 0] = f2bf(v.x);
    tile[r][c4 + j + 1] = f2bf(v.y);
    tile[r][c4 + j + 2] = f2bf(v.z);
    tile[r][c4 + j + 3] = f2bf(v.w);
  }
  __syncthreads();
  int n = t >> 2, kc = (t & 3) << 4;
  vbf8 a, b;
  #pragma unroll
  for (int j = 0; j < 8; ++j) a[j] = tile[kc + j][n];
  #pragma unroll
  for (int j = 0; j < 8; ++j) b[j] = tile[kc + 8 + j][n];
  *(vbf8*)(out + (size_t)(n0 + n) * K + k0 + kc) = a;
  *(vbf8*)(out + (size_t)(n0 + n) * K + k0 + kc + 8) = b;
}

// ---------------- im2col: x[B,3,224,224] f32 -> patches[12544, 768] bf16 -------
__global__ void k_im2col(const float* __restrict__ x, short* __restrict__ patches) {
  int tid = blockIdx.x * 256 + threadIdx.x;
  if (tid >= MPATCH * 48) return;
  int b = tid / (NPATCH * 48);
  int r = tid % (NPATCH * 48);
  int p = r / 48;
  int ck = r % 48;
  int c = ck >> 4, kh = ck & 15;
  int gy = p / 14, gx = p % 14;
  const float* src = x + ((size_t)((b * 3 + c) * 224) + gy * 16 + kh) * 224 + gx * 16;
  short* dst = patches + (size_t)(b * NPATCH + p) * KPATCH + c * 256 + kh * 16;
  float4 v0 = *(const float4*)(src);
  float4 v1 = *(const float4*)(src + 4);
  float4 v2 = *(const float4*)(src + 8);
  float4 v3 = *(const float4*)(src + 12);
  vbf8 o0, o1;
  o0[0]=f2bf(v0.x); o0[1]=f2bf(v0.y); o0[2]=f2bf(v0.z); o0[3]=f2bf(v0.w);
  o0[4]=f2bf(v1.x); o0[5]=f2bf(v1.y); o0[6]=f2bf(v1.z); o0[7]=f2bf(v1.w);
  o1[0]=f2bf(v2.x); o1[1]=f2bf(v2.y); o1[2]=f2bf(v2.z); o1[3]=f2bf(v2.w);
  o1[4]=f2bf(v3.x); o1[5]=f2bf(v3.y); o1[6]=f2bf(v3.z); o1[7]=f2bf(v3.w);
  *(vbf8*)dst = o0;
  *(vbf8*)(dst + 8) = o1;
}

// ---------------- cls token init ----------------------------------------------
__global__ void k_cls(const float* __restrict__ cls, const float* __restrict__ pos,
                      float* __restrict__ h) {
  int b = blockIdx.x, t = threadIdx.x;
  float* hr = h + (size_t)b * NTOK * DIM;
  hr[t]       = cls[t]       + pos[t];
  hr[t + 256] = cls[t + 256] + pos[t + 256];
}

// ---------------- LayerNorm over DIM=512: wave per row, 4 rows/block ----------
template<int OUTBF>
__global__ __launch_bounds__(256) void k_ln(const float* __restrict__ x,
                                            const float* __restrict__ w,
                                            const float* __restrict__ b,
                                            void* __restrict__ out) {
  int wid = threadIdx.x >> 6, lane = threadIdx.x & 63;
  int row = blockIdx.x * 4 + wid;
  const float* xr = x + (size_t)row * DIM + lane * 8;
  float4 va = *(const float4*)xr;
  float4 vb = *(const float4*)(xr + 4);
  float s  = va.x + va.y + va.z + va.w + vb.x + vb.y + vb.z + vb.w;
  float ss = va.x*va.x + va.y*va.y + va.z*va.z + va.w*va.w
           + vb.x*vb.x + vb.y*vb.y + vb.z*vb.z + vb.w*vb.w;
  #pragma unroll
  for (int o = 32; o > 0; o >>= 1) { s += __shfl_xor(s, o); ss += __shfl_xor(ss, o); }
  float mu = s * (1.0f / DIM);
  float var = ss * (1.0f / DIM) - mu * mu;
  float rs = rsqrtf(var + 1e-5f);
  float4 wa = *(const float4*)(w + lane * 8);
  float4 wb = *(const float4*)(w + lane * 8 + 4);
  float4 ba = *(const float4*)(b + lane * 8);
  float4 bb = *(const float4*)(b + lane * 8 + 4);
  float y0 = (va.x - mu) * rs * wa.x + ba.x;
  float y1 = (va.y - mu) * rs * wa.y + ba.y;
  float y2 = (va.z - mu) * rs * wa.z + ba.z;
  float y3 = (va.w - mu) * rs * wa.w + ba.w;
  float y4 = (vb.x - mu) * rs * wb.x + bb.x;
  float y5 = (vb.y - mu) * rs * wb.y + bb.y;
  float y6 = (vb.z - mu) * rs * wb.z + bb.z;
  float y7 = (vb.w - mu) * rs * wb.w + bb.w;
  if (OUTBF) {
    vbf8 pk;
    pk[0]=f2bf(y0); pk[1]=f2bf(y1); pk[2]=f2bf(y2); pk[3]=f2bf(y3);
    pk[4]=f2bf(y4); pk[5]=f2bf(y5); pk[6]=f2bf(y6); pk[7]=f2bf(y7);
    *(vbf8*)((short*)out + (size_t)row * DIM + lane * 8) = pk;
  } else {
    float4 oa, ob;
    oa.x=y0; oa.y=y1; oa.z=y2; oa.w=y3;
    ob.x=y4; ob.y=y5; ob.z=y6; ob.w=y7;
    float* op = (float*)out + (size_t)row * DIM + lane * 8;
    *(float4*)op = oa;
    *(float4*)(op + 4) = ob;
  }
}

// ---------------- MFMA GEMM: WM wave-rows x 2 wave-cols, KU chunks/barrier ----
// C[M,N] = A[M,K] * Bt[N,K]^T. BM=WM*64, BN=128, threads=WM*128.
// Each wave computes 64x64 (4x4 16x16 frags). WM=4: 8-wave 256-row tile, 48KB
// LDS -> 3 blocks/CU (TLP for latency hiding). WM=2,KU=2: proven f32-class cfg.
// MODE 0: out bf16 = acc+bias; 1: bf16 gelu(acc+bias); 2: f32 +=; 3: patch-embed
template<int MODE, int WM, int KU>
__global__ __launch_bounds__(WM * 128) void k_gemm(
    const short* __restrict__ A, const short* __restrict__ Bt,
    const float* __restrict__ bias, void* __restrict__ out,
    const float* __restrict__ extra, int M, int N, int K)
{
  constexpr int BM = WM * 64;
  constexpr int BCH = 16 / (2 * WM);   // B chunks per wave
  __shared__ short As[KU][BM * 64];
  __shared__ short Bs[KU][128 * 64];
  // bijective XCD swizzle (m204): same-bm blocks cluster on one XCD's L2
  int gx = gridDim.x;
  int nwg = gx * gridDim.y;
  int orig = blockIdx.y * gx + blockIdx.x;
  int q = nwg >> 3, r = nwg & 7, xcd = orig & 7, off = orig >> 3;
  int nid = (xcd < r ? xcd * (q + 1) : r * (q + 1) + (xcd - r) * q) + off;
  int bm = nid / gx, bn = nid % gx;

  int t = threadIdx.x, wid = t >> 6, lane = t & 63;
  int wm = wid >> 1, wn = wid & 1;
  int lr = lane & 15, lk = lane >> 4;
  int srow = lane >> 3;            // 0..7
  int scol = (lane & 7) * 8;       // shorts
  vf4 acc[4][4];
  #pragma unroll
  for (int i = 0; i < 4; ++i)
    #pragma unroll
    for (int j = 0; j < 4; ++j) {
      acc[i][j][0] = 0.f; acc[i][j][1] = 0.f; acc[i][j][2] = 0.f; acc[i][j][3] = 0.f;
    }

  const short* Abase = A  + (size_t)(bm * BM  + srow) * K + scol;
  const short* Bbase = Bt + (size_t)(bn * 128 + srow) * K + scol;

  for (int k0 = 0; k0 < K; k0 += KU * 64) {
    if (k0) __syncthreads();
    #pragma unroll
    for (int u = 0; u < KU; ++u) {
      #pragma unroll
      for (int i = 0; i < 4; ++i) {        // A: 4 chunks/wave (BM/8 = 8*WM total)
        int rc = wid * 4 + i;
        gl_lds16(Abase + (size_t)(rc * 8) * K + k0 + u * 64, &As[u][rc * 512]);
      }
      #pragma unroll
      for (int i = 0; i < BCH; ++i) {      // B: 16 chunks total
        int rc = wid * BCH + i;
        gl_lds16(Bbase + (size_t)(rc * 8) * K + k0 + u * 64, &Bs[u][rc * 512]);
      }
    }
    __syncthreads();                       // single vmcnt drain per KU*64
    #pragma unroll
    for (int u = 0; u < KU; ++u) {
      #pragma unroll
      for (int s = 0; s < 2; ++s) {
        vbf8 af[4], bfr[4];
        #pragma unroll
        for (int i = 0; i < 4; ++i)
          af[i] = *(const vbf8*)&As[u][(wm * 64 + i * 16 + lr) * 64 + s * 32 + lk * 8];
        #pragma unroll
        for (int j = 0; j < 4; ++j)
          bfr[j] = *(const vbf8*)&Bs[u][(wn * 64 + j * 16 + lr) * 64 + s * 32 + lk * 8];
        #pragma unroll
        for (int i = 0; i < 4; ++i)
          #pragma unroll
          for (int j = 0; j < 4; ++j)
            acc[i][j] = __builtin_amdgcn_mfma_f32_16x16x32_bf16(af[i], bfr[j], acc[i][j], 0, 0, 0);
      }
    }
  }

  int rbase = bm * BM + wm * 64;
  int cbase = bn * 128 + wn * 64;
  #pragma unroll
  for (int i = 0; i < 4; ++i) {
    #pragma unroll
    for (int j = 0; j < 4; ++j) {
      int col = cbase + j * 16 + lr;
      float bs = bias[col];
      #pragma unroll
      for (int z = 0; z < 4; ++z) {
        int row = rbase + i * 16 + lk * 4 + z;
        if (row < M) {
          float v = acc[i][j][z] + bs;
          if (MODE == 0) {
            ((short*)out)[(size_t)row * N + col] = f2bf(v);
          } else if (MODE == 1) {
            float g = 0.5f * v * (1.f + erff(v * 0.70710678118f));
            ((short*)out)[(size_t)row * N + col] = f2bf(g);
          } else if (MODE == 2) {
            float* hp = (float*)out + (size_t)row * N + col;
            *hp = *hp + v;
          } else {
            int b_ = row / NPATCH, p = row - b_ * NPATCH;
            ((float*)out)[((size_t)b_ * NTOK + 1 + p) * DIM + col] =
                v + extra[(size_t)(1 + p) * DIM + col];
          }
        }
      }
    }
  }
}

// ---------------- MFMA flash attention: block per (batch, head) ---------------
// S^T = K*Q^T (swapped operands), softmax in-register, P staged per-wave in LDS,
// V^T staged per-block (XOR-swizzled), O^T = V^T*P^T.  (R10 version, no setprio)
#define VSTR 232   // shorts per Vt/Pt row (224 cols + pad; stride 16B-aligned)
__global__ __launch_bounds__(256) void k_attn(const short* __restrict__ qkv,
                                              short* __restrict__ o) {
  int h = blockIdx.x, b = blockIdx.y;
  __shared__ short Vt[64 * VSTR];          // V^T [dv 64][k 224], col ^ ((dv>>3)&3)<<3
  __shared__ short Pt[4][16 * VSTR];       // per-wave P [q 16][k 224]
  int t = threadIdx.x, wid = t >> 6, lane = t & 63;
  int lq = lane & 15, g4 = lane >> 4;
  const size_t base = (size_t)(b * NTOK) * 1536 + h * 64;

  // stage V^T (zero cols >= 197)
  vbf8 vz;
  #pragma unroll
  for (int j = 0; j < 8; ++j) vz[j] = 0;
  for (int idx = t; idx < 224 * 8; idx += 256) {
    int r = idx >> 3, c8 = idx & 7;
    vbf8 v = vz;
    if (r < NTOK) v = *(const vbf8*)(qkv + base + (size_t)r * 1536 + 1024 + c8 * 8);
    int cs = r ^ ((c8 & 3) << 3);
    #pragma unroll
    for (int j = 0; j < 8; ++j) Vt[(c8 * 8 + j) * VSTR + cs] = v[j];
  }
  __syncthreads();

  short* Pw = &Pt[wid][0];
  for (int qt = wid; qt < 13; qt += 4) {
    const short* qp = qkv + base + (size_t)(qt * 16 + lq) * 1536 + g4 * 8;
    vbf8 qf0 = *(const vbf8*)qp;
    vbf8 qf1 = *(const vbf8*)(qp + 32);
    float sc[13][4];
    #pragma unroll
    for (int kt = 0; kt < 13; ++kt) {
      const short* kp = qkv + base + (size_t)(kt * 16 + lq) * 1536 + 512 + g4 * 8;
      vbf8 kf0 = *(const vbf8*)kp;
      vbf8 kf1 = *(const vbf8*)(kp + 32);
      vf4 s; s[0] = 0.f; s[1] = 0.f; s[2] = 0.f; s[3] = 0.f;
      s = __builtin_amdgcn_mfma_f32_16x16x32_bf16(kf0, qf0, s, 0, 0, 0);
      s = __builtin_amdgcn_mfma_f32_16x16x32_bf16(kf1, qf1, s, 0, 0, 0);
      #pragma unroll
      for (int z = 0; z < 4; ++z) {
        int krow = kt * 16 + g4 * 4 + z;
        sc[kt][z] = (krow < NTOK) ? s[z] * 0.125f : -1e30f;
      }
    }
    float mx = -1e30f;
    #pragma unroll
    for (int kt = 0; kt < 13; ++kt)
      #pragma unroll
      for (int z = 0; z < 4; ++z) mx = fmaxf(mx, sc[kt][z]);
    mx = fmaxf(mx, __shfl_xor(mx, 16));
    mx = fmaxf(mx, __shfl_xor(mx, 32));
    float sum = 0.f;
    #pragma unroll
    for (int kt = 0; kt < 13; ++kt)
      #pragma unroll
      for (int z = 0; z < 4; ++z) {
        float e = __expf(sc[kt][z] - mx);
        sc[kt][z] = e;
        sum += e;
      }
    sum += __shfl_xor(sum, 16);
    sum += __shfl_xor(sum, 32);
    float inv = 1.f / sum;
    #pragma unroll
    for (int kt = 0; kt < 13; ++kt) {
      *(short4*)&Pw[lq * VSTR + kt * 16 + g4 * 4] =
          make_short4(f2bf(sc[kt][0]), f2bf(sc[kt][1]), f2bf(sc[kt][2]), f2bf(sc[kt][3]));
    }
    *(short4*)&Pw[lq * VSTR + 208 + g4 * 4] = make_short4(0, 0, 0, 0); // k 208..223
    vf4 oacc[4];
    #pragma unroll
    for (int dt = 0; dt < 4; ++dt) { oacc[dt][0]=0.f; oacc[dt][1]=0.f; oacc[dt][2]=0.f; oacc[dt][3]=0.f; }
    #pragma unroll
    for (int u = 0; u < 7; ++u) {
      vbf8 pb = *(const vbf8*)&Pw[lq * VSTR + u * 32 + g4 * 8];
      #pragma unroll
      for (int dt = 0; dt < 4; ++dt) {
        int swz = ((dt * 2 + (lq >> 3)) & 3) << 3;
        vbf8 va = *(const vbf8*)&Vt[(dt * 16 + lq) * VSTR + ((u * 32 + g4 * 8) ^ swz)];
        oacc[dt] = __builtin_amdgcn_mfma_f32_16x16x32_bf16(va, pb, oacc[dt], 0, 0, 0);
      }
    }
    int qrow = qt * 16 + lq;
    if (qrow < NTOK) {
      short* op = o + ((size_t)(b * NTOK) + qrow) * DIM + h * 64 + g4 * 4;
      #pragma unroll
      for (int dt = 0; dt < 4; ++dt)
        *(short4*)(op + dt * 16) = make_short4(f2bf(oacc[dt][0] * inv), f2bf(oacc[dt][1] * inv),
                                               f2bf(oacc[dt][2] * inv), f2bf(oacc[dt][3] * inv));
    }
  }
}

// ------------------------------- launch ---------------------------------------
extern "C" void kernel_launch(void* const* d_in, const int* in_sizes, int n_in,
                              void* d_out, int out_size, void* d_ws, size_t ws_size,
                              hipStream_t stream) {
  (void)in_sizes; (void)n_in; (void)out_size; (void)ws_size;
  const float* x      = (const float*)d_in[0];
  const float* conv_w = (const float*)d_in[1];
  const float* conv_b = (const float*)d_in[2];
  const float* cls    = (const float*)d_in[3];
  const float* pos    = (const float*)d_in[4];
  const float* ln1_w  = (const float*)d_in[5];
  const float* ln1_b  = (const float*)d_in[6];
  const float* qkv_w  = (const float*)d_in[7];
  const float* qkv_b  = (const float*)d_in[8];
  const float* proj_w = (const float*)d_in[9];
  const float* proj_b = (const float*)d_in[10];
  const float* ln2_w  = (const float*)d_in[11];
  const float* ln2_b  = (const float*)d_in[12];
  const float* fc1_w  = (const float*)d_in[13];
  const float* fc1_b  = (const float*)d_in[14];
  const float* fc2_w  = (const float*)d_in[15];
  const float* fc2_b  = (const float*)d_in[16];
  const float* norm_w = (const float*)d_in[17];
  const float* norm_b = (const float*)d_in[18];

  short* conv_wT = (short*)d_ws;                       // [512][768]
  short* qkv_wT  = conv_wT + (size_t)512 * 768;        // 4x[1536][512]
  short* proj_wT = qkv_wT  + (size_t)4 * 1536 * 512;   // 4x[512][512]
  short* fc1_wT  = proj_wT + (size_t)4 * 512 * 512;    // 4x[1024][512]
  short* fc2_wT  = fc1_wT  + (size_t)4 * 512 * 1024;   // 4x[512][1024]
  short* y_bf    = fc2_wT  + (size_t)4 * 1024 * 512;   // [12608][512]
  short* o_bf    = y_bf    + (size_t)MTOK * 512;       // [12608][512]
  short* big     = o_bf    + (size_t)MTOK * 512;       // patches / qkv / mlp alias
  float* h       = (float*)(big + (size_t)MTOK * 1536);// [12608][512] f32

  k_cvt_t<<<dim3(8, 12, 1), 256, 0, stream>>>(conv_w, conv_wT, 768, 512);
  k_cvt_t<<<dim3(24, 8, 4), 256, 0, stream>>>(qkv_w, qkv_wT, 512, 1536);
  k_cvt_t<<<dim3(8, 8, 4), 256, 0, stream>>>(proj_w, proj_wT, 512, 512);
  k_cvt_t<<<dim3(16, 8, 4), 256, 0, stream>>>(fc1_w, fc1_wT, 512, 1024);
  k_cvt_t<<<dim3(8, 16, 4), 256, 0, stream>>>(fc2_w, fc2_wT, 1024, 512);

  k_im2col<<<2352, 256, 0, stream>>>(x, big);
  k_cls<<<64, 256, 0, stream>>>(cls, pos, h);
  k_gemm<3, 2, 2><<<dim3(4, 98), 256, 0, stream>>>(big, conv_wT, conv_b, h, pos,
                                                   MPATCH, 512, 768);
  for (int i = 0; i < 4; ++i) {
    k_ln<1><<<MTOK / 4, 256, 0, stream>>>(h, ln1_w + i * 512, ln1_b + i * 512, y_bf);
    k_gemm<0, 4, 1><<<dim3(12, 50), 512, 0, stream>>>(y_bf, qkv_wT + (size_t)i * 512 * 1536,
                                                      qkv_b + i * 1536, big, nullptr,
                                                      MTOK, 1536, 512);
    k_attn<<<dim3(8, 64), 256, 0, stream>>>(big, o_bf);
    k_gemm<2, 2, 2><<<dim3(4, 99), 256, 0, stream>>>(o_bf, proj_wT + (size_t)i * 512 * 512,
                                                     proj_b + i * 512, h, nullptr,
                                                     MTOK, 512, 512);
    k_ln<1><<<MTOK / 4, 256, 0, stream>>>(h, ln2_w + i * 512, ln2_b + i * 512, y_bf);
    k_gemm<1, 4, 1><<<dim3(8, 50), 512, 0, stream>>>(y_bf, fc1_wT + (size_t)i * 512 * 1024,
                                                     fc1_b + i * 1024, big, nullptr,
                                                     MTOK, 1024, 512);
    k_gemm<2, 2, 2><<<dim3(4, 99), 256, 0, stream>>>(big, fc2_wT + (size_t)i * 1024 * 512,
                                                     fc2_b + i * 512, h, nullptr,
                                                     MTOK, 512, 1024);
  }
  k_ln<0><<<MTOK / 4, 256, 0, stream>>>(h, norm_w, norm_b, d_out);
}

// Round 15
// 895.293 us; speedup vs baseline: 1.1193x; 1.1193x over previous
//
#include <hip/hip_runtime.h>
#include <hip/hip_bf16.h>

#define HEADS 8
#define DIM 512
#define HID 1024
#define NTOK 197
#define NPATCH 196
#define BATCH 64
#define MTOK (BATCH*NTOK)     // 12608
#define MPATCH (BATCH*NPATCH) // 12544
#define KPATCH 768

typedef __attribute__((ext_vector_type(8))) short vbf8;
typedef __attribute__((ext_vector_type(4))) float vf4;

__device__ inline float bf2f(short u) {
  union { unsigned int i; float f; } v; v.i = ((unsigned int)(unsigned short)u) << 16; return v.f;
}
__device__ inline short f2bf(float f) {
  union { float f; unsigned int i; } u; u.f = f;
  unsigned int r = u.i + 0x7fffu + ((u.i >> 16) & 1u);
  return (short)(r >> 16);
}

__device__ inline void gl_lds16(const void* g, void* l) {
  __builtin_amdgcn_global_load_lds(
      (const __attribute__((address_space(1))) void*)g,
      (__attribute__((address_space(3))) void*)l, 16, 0, 0);
}

// ---------------- weight convert + transpose: in[K][N] f32 -> out[N][K] bf16 ----
__global__ void k_cvt_t(const float* __restrict__ in, short* __restrict__ out, int K, int N) {
  int slice = blockIdx.z;
  in  += (size_t)slice * K * N;
  out += (size_t)slice * K * N;
  __shared__ short tile[64][72];
  int t = threadIdx.x;
  int k0 = blockIdx.y * 64, n0 = blockIdx.x * 64;
  int r = t >> 2, c4 = (t & 3) << 4;
  #pragma unroll
  for (int j = 0; j < 16; j += 4) {
    float4 v = *(const float4*)(in + (size_t)(k0 + r) * N + n0 + c4 + j);
    tile[r][c4 + j + 0] = f2bf(v.x);
    tile[r][c4 + j + 1] = f2bf(v.y);
    tile[r][c4 + j + 2] = f2bf(v.z);
    tile[r][c4 + j + 3] = f2bf(v.w);
  }
  __syncthreads();
  int n = t >> 2, kc = (t & 3) << 4;
  vbf8 a, b;
  #pragma unroll
  for (int j = 0; j < 8; ++j) a[j] = tile[kc + j][n];
  #pragma unroll
  for (int j = 0; j < 8; ++j) b[j] = tile[kc + 8 + j][n];
  *(vbf8*)(out + (size_t)(n0 + n) * K + k0 + kc) = a;
  *(vbf8*)(out + (size_t)(n0 + n) * K + k0 + kc + 8) = b;
}

// ---------------- im2col: x[B,3,224,224] f32 -> patches[12544, 768] bf16 -------
__global__ void k_im2col(const float* __restrict__ x, short* __restrict__ patches) {
  int tid = blockIdx.x * 256 + threadIdx.x;
  if (tid >= MPATCH * 48) return;
  int b = tid / (NPATCH * 48);
  int r = tid % (NPATCH * 48);
  int p = r / 48;
  int ck = r % 48;
  int c = ck >> 4, kh = ck & 15;
  int gy = p / 14, gx = p % 14;
  const float* src = x + ((size_t)((b * 3 + c) * 224) + gy * 16 + kh) * 224 + gx * 16;
  short* dst = patches + (size_t)(b * NPATCH + p) * KPATCH + c * 256 + kh * 16;
  float4 v0 = *(const float4*)(src);
  float4 v1 = *(const float4*)(src + 4);
  float4 v2 = *(const float4*)(src + 8);
  float4 v3 = *(const float4*)(src + 12);
  vbf8 o0, o1;
  o0[0]=f2bf(v0.x); o0[1]=f2bf(v0.y); o0[2]=f2bf(v0.z); o0[3]=f2bf(v0.w);
  o0[4]=f2bf(v1.x); o0[5]=f2bf(v1.y); o0[6]=f2bf(v1.z); o0[7]=f2bf(v1.w);
  o1[0]=f2bf(v2.x); o1[1]=f2bf(v2.y); o1[2]=f2bf(v2.z); o1[3]=f2bf(v2.w);
  o1[4]=f2bf(v3.x); o1[5]=f2bf(v3.y); o1[6]=f2bf(v3.z); o1[7]=f2bf(v3.w);
  *(vbf8*)dst = o0;
  *(vbf8*)(dst + 8) = o1;
}

// ---------------- cls token init ----------------------------------------------
__global__ void k_cls(const float* __restrict__ cls, const float* __restrict__ pos,
                      float* __restrict__ h) {
  int b = blockIdx.x, t = threadIdx.x;
  float* hr = h + (size_t)b * NTOK * DIM;
  hr[t]       = cls[t]       + pos[t];
  hr[t + 256] = cls[t + 256] + pos[t + 256];
}

// ---------------- LayerNorm over DIM=512: wave per row, 4 rows/block ----------
template<int OUTBF>
__global__ __launch_bounds__(256) void k_ln(const float* __restrict__ x,
                                            const float* __restrict__ w,
                                            const float* __restrict__ b,
                                            void* __restrict__ out) {
  int wid = threadIdx.x >> 6, lane = threadIdx.x & 63;
  int row = blockIdx.x * 4 + wid;
  const float* xr = x + (size_t)row * DIM + lane * 8;
  float4 va = *(const float4*)xr;
  float4 vb = *(const float4*)(xr + 4);
  float s  = va.x + va.y + va.z + va.w + vb.x + vb.y + vb.z + vb.w;
  float ss = va.x*va.x + va.y*va.y + va.z*va.z + va.w*va.w
           + vb.x*vb.x + vb.y*vb.y + vb.z*vb.z + vb.w*vb.w;
  #pragma unroll
  for (int o = 32; o > 0; o >>= 1) { s += __shfl_xor(s, o); ss += __shfl_xor(ss, o); }
  float mu = s * (1.0f / DIM);
  float var = ss * (1.0f / DIM) - mu * mu;
  float rs = rsqrtf(var + 1e-5f);
  float4 wa = *(const float4*)(w + lane * 8);
  float4 wb = *(const float4*)(w + lane * 8 + 4);
  float4 ba = *(const float4*)(b + lane * 8);
  float4 bb = *(const float4*)(b + lane * 8 + 4);
  float y0 = (va.x - mu) * rs * wa.x + ba.x;
  float y1 = (va.y - mu) * rs * wa.y + ba.y;
  float y2 = (va.z - mu) * rs * wa.z + ba.z;
  float y3 = (va.w - mu) * rs * wa.w + ba.w;
  float y4 = (vb.x - mu) * rs * wb.x + bb.x;
  float y5 = (vb.y - mu) * rs * wb.y + bb.y;
  float y6 = (vb.z - mu) * rs * wb.z + bb.z;
  float y7 = (vb.w - mu) * rs * wb.w + bb.w;
  if (OUTBF) {
    vbf8 pk;
    pk[0]=f2bf(y0); pk[1]=f2bf(y1); pk[2]=f2bf(y2); pk[3]=f2bf(y3);
    pk[4]=f2bf(y4); pk[5]=f2bf(y5); pk[6]=f2bf(y6); pk[7]=f2bf(y7);
    *(vbf8*)((short*)out + (size_t)row * DIM + lane * 8) = pk;
  } else {
    float4 oa, ob;
    oa.x=y0; oa.y=y1; oa.z=y2; oa.w=y3;
    ob.x=y4; ob.y=y5; ob.z=y6; ob.w=y7;
    float* op = (float*)out + (size_t)row * DIM + lane * 8;
    *(float4*)op = oa;
    *(float4*)(op + 4) = ob;
  }
}

// ---------------- MFMA GEMM (best config: R3 core, KU=2, XCD swizzle) ---------
// C[M,N] = A[M,K] * Bt[N,K]^T. BM=BN=128, 256 thr (2x2 waves, 4x4 frags).
// KU=2: stage 2x64-K chunks, one vmcnt-drain pair per 128-K (64KB LDS).
// MODE 0: out bf16 = acc+bias; 1: bf16 gelu(acc+bias); 2: f32 +=; 3: patch-embed
template<int MODE, int KU>
__global__ __launch_bounds__(256) void k_gemm(
    const short* __restrict__ A, const short* __restrict__ Bt,
    const float* __restrict__ bias, void* __restrict__ out,
    const float* __restrict__ extra, int M, int N, int K)
{
  __shared__ short As[KU][128 * 64];
  __shared__ short Bs[KU][128 * 64];
  // bijective XCD swizzle (m204): same-bm blocks cluster on one XCD's L2
  int gx = gridDim.x;
  int nwg = gx * gridDim.y;
  int orig = blockIdx.y * gx + blockIdx.x;
  int q = nwg >> 3, r = nwg & 7, xcd = orig & 7, off = orig >> 3;
  int nid = (xcd < r ? xcd * (q + 1) : r * (q + 1) + (xcd - r) * q) + off;
  int bm = nid / gx, bn = nid % gx;

  int t = threadIdx.x, wid = t >> 6, lane = t & 63;
  int wm = wid >> 1, wn = wid & 1;
  int lr = lane & 15, lk = lane >> 4;
  int srow = lane >> 3;            // 0..7
  int scol = (lane & 7) * 8;       // shorts
  vf4 acc[4][4];
  #pragma unroll
  for (int i = 0; i < 4; ++i)
    #pragma unroll
    for (int j = 0; j < 4; ++j) {
      acc[i][j][0] = 0.f; acc[i][j][1] = 0.f; acc[i][j][2] = 0.f; acc[i][j][3] = 0.f;
    }

  const short* Abase = A  + (size_t)(bm * 128 + srow) * K + scol;
  const short* Bbase = Bt + (size_t)(bn * 128 + srow) * K + scol;

  for (int k0 = 0; k0 < K; k0 += KU * 64) {
    if (k0) __syncthreads();
    #pragma unroll
    for (int u = 0; u < KU; ++u) {
      #pragma unroll
      for (int i = 0; i < 4; ++i) {
        int rc = wid * 4 + i;                     // 8-row chunk id (0..15)
        gl_lds16(Abase + (size_t)(rc * 8) * K + k0 + u * 64, &As[u][rc * 512]);
        gl_lds16(Bbase + (size_t)(rc * 8) * K + k0 + u * 64, &Bs[u][rc * 512]);
      }
    }
    __syncthreads();                              // single vmcnt drain per KU*64
    #pragma unroll
    for (int u = 0; u < KU; ++u) {
      #pragma unroll
      for (int s = 0; s < 2; ++s) {
        vbf8 af[4], bfr[4];
        #pragma unroll
        for (int i = 0; i < 4; ++i)
          af[i] = *(const vbf8*)&As[u][(wm * 64 + i * 16 + lr) * 64 + s * 32 + lk * 8];
        #pragma unroll
        for (int j = 0; j < 4; ++j)
          bfr[j] = *(const vbf8*)&Bs[u][(wn * 64 + j * 16 + lr) * 64 + s * 32 + lk * 8];
        #pragma unroll
        for (int i = 0; i < 4; ++i)
          #pragma unroll
          for (int j = 0; j < 4; ++j)
            acc[i][j] = __builtin_amdgcn_mfma_f32_16x16x32_bf16(af[i], bfr[j], acc[i][j], 0, 0, 0);
      }
    }
  }

  int rbase = bm * 128 + wm * 64;
  int cbase = bn * 128 + wn * 64;
  #pragma unroll
  for (int i = 0; i < 4; ++i) {
    #pragma unroll
    for (int j = 0; j < 4; ++j) {
      int col = cbase + j * 16 + lr;
      float bs = bias[col];
      #pragma unroll
      for (int z = 0; z < 4; ++z) {
        int row = rbase + i * 16 + lk * 4 + z;
        if (row < M) {
          float v = acc[i][j][z] + bs;
          if (MODE == 0) {
            ((short*)out)[(size_t)row * N + col] = f2bf(v);
          } else if (MODE == 1) {
            float g = 0.5f * v * (1.f + erff(v * 0.70710678118f));
            ((short*)out)[(size_t)row * N + col] = f2bf(g);
          } else if (MODE == 2) {
            float* hp = (float*)out + (size_t)row * N + col;
            *hp = *hp + v;
          } else {
            int b_ = row / NPATCH, p = row - b_ * NPATCH;
            ((float*)out)[((size_t)b_ * NTOK + 1 + p) * DIM + col] =
                v + extra[(size_t)(1 + p) * DIM + col];
          }
        }
      }
    }
  }
}

// ---------------- MFMA flash attention: block per (batch, head) ---------------
// S^T = K*Q^T (swapped operands), softmax in-register, P staged per-wave in LDS,
// V^T staged per-block (XOR-swizzled), O^T = V^T*P^T.
#define VSTR 232   // shorts per Vt/Pt row (224 cols + pad; stride 16B-aligned)
__global__ __launch_bounds__(256) void k_attn(const short* __restrict__ qkv,
                                              short* __restrict__ o) {
  int h = blockIdx.x, b = blockIdx.y;
  __shared__ short Vt[64 * VSTR];          // V^T [dv 64][k 224], col ^ ((dv>>3)&3)<<3
  __shared__ short Pt[4][16 * VSTR];       // per-wave P [q 16][k 224]
  int t = threadIdx.x, wid = t >> 6, lane = t & 63;
  int lq = lane & 15, g4 = lane >> 4;
  const size_t base = (size_t)(b * NTOK) * 1536 + h * 64;

  // stage V^T (zero cols >= 197)
  vbf8 vz;
  #pragma unroll
  for (int j = 0; j < 8; ++j) vz[j] = 0;
  for (int idx = t; idx < 224 * 8; idx += 256) {
    int r = idx >> 3, c8 = idx & 7;
    vbf8 v = vz;
    if (r < NTOK) v = *(const vbf8*)(qkv + base + (size_t)r * 1536 + 1024 + c8 * 8);
    int cs = r ^ ((c8 & 3) << 3);
    #pragma unroll
    for (int j = 0; j < 8; ++j) Vt[(c8 * 8 + j) * VSTR + cs] = v[j];
  }
  __syncthreads();

  short* Pw = &Pt[wid][0];
  for (int qt = wid; qt < 13; qt += 4) {
    const short* qp = qkv + base + (size_t)(qt * 16 + lq) * 1536 + g4 * 8;
    vbf8 qf0 = *(const vbf8*)qp;
    vbf8 qf1 = *(const vbf8*)(qp + 32);
    float sc[13][4];
    #pragma unroll
    for (int kt = 0; kt < 13; ++kt) {
      const short* kp = qkv + base + (size_t)(kt * 16 + lq) * 1536 + 512 + g4 * 8;
      vbf8 kf0 = *(const vbf8*)kp;
      vbf8 kf1 = *(const vbf8*)(kp + 32);
      vf4 s; s[0] = 0.f; s[1] = 0.f; s[2] = 0.f; s[3] = 0.f;
      s = __builtin_amdgcn_mfma_f32_16x16x32_bf16(kf0, qf0, s, 0, 0, 0);
      s = __builtin_amdgcn_mfma_f32_16x16x32_bf16(kf1, qf1, s, 0, 0, 0);
      #pragma unroll
      for (int z = 0; z < 4; ++z) {
        int krow = kt * 16 + g4 * 4 + z;
        sc[kt][z] = (krow < NTOK) ? s[z] * 0.125f : -1e30f;
      }
    }
    float mx = -1e30f;
    #pragma unroll
    for (int kt = 0; kt < 13; ++kt)
      #pragma unroll
      for (int z = 0; z < 4; ++z) mx = fmaxf(mx, sc[kt][z]);
    mx = fmaxf(mx, __shfl_xor(mx, 16));
    mx = fmaxf(mx, __shfl_xor(mx, 32));
    float sum = 0.f;
    #pragma unroll
    for (int kt = 0; kt < 13; ++kt)
      #pragma unroll
      for (int z = 0; z < 4; ++z) {
        float e = __expf(sc[kt][z] - mx);
        sc[kt][z] = e;
        sum += e;
      }
    sum += __shfl_xor(sum, 16);
    sum += __shfl_xor(sum, 32);
    float inv = 1.f / sum;
    #pragma unroll
    for (int kt = 0; kt < 13; ++kt) {
      *(short4*)&Pw[lq * VSTR + kt * 16 + g4 * 4] =
          make_short4(f2bf(sc[kt][0]), f2bf(sc[kt][1]), f2bf(sc[kt][2]), f2bf(sc[kt][3]));
    }
    *(short4*)&Pw[lq * VSTR + 208 + g4 * 4] = make_short4(0, 0, 0, 0); // k 208..223
    vf4 oacc[4];
    #pragma unroll
    for (int dt = 0; dt < 4; ++dt) { oacc[dt][0]=0.f; oacc[dt][1]=0.f; oacc[dt][2]=0.f; oacc[dt][3]=0.f; }
    #pragma unroll
    for (int u = 0; u < 7; ++u) {
      vbf8 pb = *(const vbf8*)&Pw[lq * VSTR + u * 32 + g4 * 8];
      #pragma unroll
      for (int dt = 0; dt < 4; ++dt) {
        int swz = ((dt * 2 + (lq >> 3)) & 3) << 3;
        vbf8 va = *(const vbf8*)&Vt[(dt * 16 + lq) * VSTR + ((u * 32 + g4 * 8) ^ swz)];
        oacc[dt] = __builtin_amdgcn_mfma_f32_16x16x32_bf16(va, pb, oacc[dt], 0, 0, 0);
      }
    }
    int qrow = qt * 16 + lq;
    if (qrow < NTOK) {
      short* op = o + ((size_t)(b * NTOK) + qrow) * DIM + h * 64 + g4 * 4;
      #pragma unroll
      for (int dt = 0; dt < 4; ++dt)
        *(short4*)(op + dt * 16) = make_short4(f2bf(oacc[dt][0] * inv), f2bf(oacc[dt][1] * inv),
                                               f2bf(oacc[dt][2] * inv), f2bf(oacc[dt][3] * inv));
    }
  }
}

// ------------------------------- launch ---------------------------------------
extern "C" void kernel_launch(void* const* d_in, const int* in_sizes, int n_in,
                              void* d_out, int out_size, void* d_ws, size_t ws_size,
                              hipStream_t stream) {
  (void)in_sizes; (void)n_in; (void)out_size; (void)ws_size;
  const float* x      = (const float*)d_in[0];
  const float* conv_w = (const float*)d_in[1];
  const float* conv_b = (const float*)d_in[2];
  const float* cls    = (const float*)d_in[3];
  const float* pos    = (const float*)d_in[4];
  const float* ln1_w  = (const float*)d_in[5];
  const float* ln1_b  = (const float*)d_in[6];
  const float* qkv_w  = (const float*)d_in[7];
  const float* qkv_b  = (const float*)d_in[8];
  const float* proj_w = (const float*)d_in[9];
  const float* proj_b = (const float*)d_in[10];
  const float* ln2_w  = (const float*)d_in[11];
  const float* ln2_b  = (const float*)d_in[12];
  const float* fc1_w  = (const float*)d_in[13];
  const float* fc1_b  = (const float*)d_in[14];
  const float* fc2_w  = (const float*)d_in[15];
  const float* fc2_b  = (const float*)d_in[16];
  const float* norm_w = (const float*)d_in[17];
  const float* norm_b = (const float*)d_in[18];

  short* conv_wT = (short*)d_ws;                       // [512][768]
  short* qkv_wT  = conv_wT + (size_t)512 * 768;        // 4x[1536][512]
  short* proj_wT = qkv_wT  + (size_t)4 * 1536 * 512;   // 4x[512][512]
  short* fc1_wT  = proj_wT + (size_t)4 * 512 * 512;    // 4x[1024][512]
  short* fc2_wT  = fc1_wT  + (size_t)4 * 512 * 1024;   // 4x[512][1024]
  short* y_bf    = fc2_wT  + (size_t)4 * 1024 * 512;   // [12608][512]
  short* o_bf    = y_bf    + (size_t)MTOK * 512;       // [12608][512]
  short* big     = o_bf    + (size_t)MTOK * 512;       // patches / qkv / mlp alias
  float* h       = (float*)(big + (size_t)MTOK * 1536);// [12608][512] f32

  k_cvt_t<<<dim3(8, 12, 1), 256, 0, stream>>>(conv_w, conv_wT, 768, 512);
  k_cvt_t<<<dim3(24, 8, 4), 256, 0, stream>>>(qkv_w, qkv_wT, 512, 1536);
  k_cvt_t<<<dim3(8, 8, 4), 256, 0, stream>>>(proj_w, proj_wT, 512, 512);
  k_cvt_t<<<dim3(16, 8, 4), 256, 0, stream>>>(fc1_w, fc1_wT, 512, 1024);
  k_cvt_t<<<dim3(8, 16, 4), 256, 0, stream>>>(fc2_w, fc2_wT, 1024, 512);

  k_im2col<<<2352, 256, 0, stream>>>(x, big);
  k_cls<<<64, 256, 0, stream>>>(cls, pos, h);
  k_gemm<3, 2><<<dim3(4, 98), 256, 0, stream>>>(big, conv_wT, conv_b, h, pos,
                                                MPATCH, 512, 768);
  for (int i = 0; i < 4; ++i) {
    k_ln<1><<<MTOK / 4, 256, 0, stream>>>(h, ln1_w + i * 512, ln1_b + i * 512, y_bf);
    k_gemm<0, 2><<<dim3(12, 99), 256, 0, stream>>>(y_bf, qkv_wT + (size_t)i * 512 * 1536,
                                                   qkv_b + i * 1536, big, nullptr,
                                                   MTOK, 1536, 512);
    k_attn<<<dim3(8, 64), 256, 0, stream>>>(big, o_bf);
    k_gemm<2, 2><<<dim3(4, 99), 256, 0, stream>>>(o_bf, proj_wT + (size_t)i * 512 * 512,
                                                  proj_b + i * 512, h, nullptr,
                                                  MTOK, 512, 512);
    k_ln<1><<<MTOK / 4, 256, 0, stream>>>(h, ln2_w + i * 512, ln2_b + i * 512, y_bf);
    k_gemm<1, 2><<<dim3(8, 99), 256, 0, stream>>>(y_bf, fc1_wT + (size_t)i * 512 * 1024,
                                                  fc1_b + i * 1024, big, nullptr,
                                                  MTOK, 1024, 512);
    k_gemm<2, 2><<<dim3(4, 99), 256, 0, stream>>>(big, fc2_wT + (size_t)i * 1024 * 512,
                                                  fc2_b + i * 512, h, nullptr,
                                                  MTOK, 512, 1024);
  }
  k_ln<0><<<MTOK / 4, 256, 0, stream>>>(h, norm_w, norm_b, d_out);
}

// Round 16
// 857.286 us; speedup vs baseline: 1.1689x; 1.0443x over previous
//
#include <hip/hip_runtime.h>
#include <hip/hip_bf16.h>

#define HEADS 8
#define DIM 512
#define HID 1024
#define NTOK 197
#define NPATCH 196
#define BATCH 64
#define MTOK (BATCH*NTOK)     // 12608
#define MPATCH (BATCH*NPATCH) // 12544
#define KPATCH 768

typedef __attribute__((ext_vector_type(8))) short vbf8;
typedef __attribute__((ext_vector_type(4))) float vf4;

__device__ inline float bf2f(short u) {
  union { unsigned int i; float f; } v; v.i = ((unsigned int)(unsigned short)u) << 16; return v.f;
}
__device__ inline short f2bf(float f) {
  union { float f; unsigned int i; } u; u.f = f;
  unsigned int r = u.i + 0x7fffu + ((u.i >> 16) & 1u);
  return (short)(r >> 16);
}

__device__ inline void gl_lds16(const void* g, void* l) {
  __builtin_amdgcn_global_load_lds(
      (const __attribute__((address_space(1))) void*)g,
      (__attribute__((address_space(3))) void*)l, 16, 0, 0);
}

// ---------------- weight convert + transpose: in[K][N] f32 -> out[N][K] bf16 ----
__global__ void k_cvt_t(const float* __restrict__ in, short* __restrict__ out, int K, int N) {
  int slice = blockIdx.z;
  in  += (size_t)slice * K * N;
  out += (size_t)slice * K * N;
  __shared__ short tile[64][72];
  int t = threadIdx.x;
  int k0 = blockIdx.y * 64, n0 = blockIdx.x * 64;
  int r = t >> 2, c4 = (t & 3) << 4;
  #pragma unroll
  for (int j = 0; j < 16; j += 4) {
    float4 v = *(const float4*)(in + (size_t)(k0 + r) * N + n0 + c4 + j);
    tile[r][c4 + j + 0] = f2bf(v.x);
    tile[r][c4 + j + 1] = f2bf(v.y);
    tile[r][c4 + j + 2] = f2bf(v.z);
    tile[r][c4 + j + 3] = f2bf(v.w);
  }
  __syncthreads();
  int n = t >> 2, kc = (t & 3) << 4;
  vbf8 a, b;
  #pragma unroll
  for (int j = 0; j < 8; ++j) a[j] = tile[kc + j][n];
  #pragma unroll
  for (int j = 0; j < 8; ++j) b[j] = tile[kc + 8 + j][n];
  *(vbf8*)(out + (size_t)(n0 + n) * K + k0 + kc) = a;
  *(vbf8*)(out + (size_t)(n0 + n) * K + k0 + kc + 8) = b;
}

// ---------------- im2col: x[B,3,224,224] f32 -> patches[12544, 768] bf16 -------
__global__ void k_im2col(const float* __restrict__ x, short* __restrict__ patches) {
  int tid = blockIdx.x * 256 + threadIdx.x;
  if (tid >= MPATCH * 48) return;
  int b = tid / (NPATCH * 48);
  int r = tid % (NPATCH * 48);
  int p = r / 48;
  int ck = r % 48;
  int c = ck >> 4, kh = ck & 15;
  int gy = p / 14, gx = p % 14;
  const float* src = x + ((size_t)((b * 3 + c) * 224) + gy * 16 + kh) * 224 + gx * 16;
  short* dst = patches + (size_t)(b * NPATCH + p) * KPATCH + c * 256 + kh * 16;
  float4 v0 = *(const float4*)(src);
  float4 v1 = *(const float4*)(src + 4);
  float4 v2 = *(const float4*)(src + 8);
  float4 v3 = *(const float4*)(src + 12);
  vbf8 o0, o1;
  o0[0]=f2bf(v0.x); o0[1]=f2bf(v0.y); o0[2]=f2bf(v0.z); o0[3]=f2bf(v0.w);
  o0[4]=f2bf(v1.x); o0[5]=f2bf(v1.y); o0[6]=f2bf(v1.z); o0[7]=f2bf(v1.w);
  o1[0]=f2bf(v2.x); o1[1]=f2bf(v2.y); o1[2]=f2bf(v2.z); o1[3]=f2bf(v2.w);
  o1[4]=f2bf(v3.x); o1[5]=f2bf(v3.y); o1[6]=f2bf(v3.z); o1[7]=f2bf(v3.w);
  *(vbf8*)dst = o0;
  *(vbf8*)(dst + 8) = o1;
}

// ---------------- cls token init (bf16 residual) -------------------------------
__global__ void k_cls(const float* __restrict__ cls, const float* __restrict__ pos,
                      short* __restrict__ h) {
  int b = blockIdx.x, t = threadIdx.x;
  short* hr = h + (size_t)b * NTOK * DIM;
  hr[t]       = f2bf(cls[t]       + pos[t]);
  hr[t + 256] = f2bf(cls[t + 256] + pos[t + 256]);
}

// ---------------- LayerNorm over DIM=512 (bf16 in): wave/row, 4 rows/block ----
template<int OUTBF>
__global__ __launch_bounds__(256) void k_ln(const short* __restrict__ x,
                                            const float* __restrict__ w,
                                            const float* __restrict__ b,
                                            void* __restrict__ out) {
  int wid = threadIdx.x >> 6, lane = threadIdx.x & 63;
  int row = blockIdx.x * 4 + wid;
  vbf8 xv = *(const vbf8*)(x + (size_t)row * DIM + lane * 8);
  float v0 = bf2f(xv[0]), v1 = bf2f(xv[1]), v2 = bf2f(xv[2]), v3 = bf2f(xv[3]);
  float v4 = bf2f(xv[4]), v5 = bf2f(xv[5]), v6 = bf2f(xv[6]), v7 = bf2f(xv[7]);
  float s  = v0 + v1 + v2 + v3 + v4 + v5 + v6 + v7;
  float ss = v0*v0 + v1*v1 + v2*v2 + v3*v3 + v4*v4 + v5*v5 + v6*v6 + v7*v7;
  #pragma unroll
  for (int o = 32; o > 0; o >>= 1) { s += __shfl_xor(s, o); ss += __shfl_xor(ss, o); }
  float mu = s * (1.0f / DIM);
  float var = ss * (1.0f / DIM) - mu * mu;
  float rs = rsqrtf(var + 1e-5f);
  float4 wa = *(const float4*)(w + lane * 8);
  float4 wb = *(const float4*)(w + lane * 8 + 4);
  float4 ba = *(const float4*)(b + lane * 8);
  float4 bb = *(const float4*)(b + lane * 8 + 4);
  float y0 = (v0 - mu) * rs * wa.x + ba.x;
  float y1 = (v1 - mu) * rs * wa.y + ba.y;
  float y2 = (v2 - mu) * rs * wa.z + ba.z;
  float y3 = (v3 - mu) * rs * wa.w + ba.w;
  float y4 = (v4 - mu) * rs * wb.x + bb.x;
  float y5 = (v5 - mu) * rs * wb.y + bb.y;
  float y6 = (v6 - mu) * rs * wb.z + bb.z;
  float y7 = (v7 - mu) * rs * wb.w + bb.w;
  if (OUTBF) {
    vbf8 pk;
    pk[0]=f2bf(y0); pk[1]=f2bf(y1); pk[2]=f2bf(y2); pk[3]=f2bf(y3);
    pk[4]=f2bf(y4); pk[5]=f2bf(y5); pk[6]=f2bf(y6); pk[7]=f2bf(y7);
    *(vbf8*)((short*)out + (size_t)row * DIM + lane * 8) = pk;
  } else {
    float4 oa, ob;
    oa.x=y0; oa.y=y1; oa.z=y2; oa.w=y3;
    ob.x=y4; ob.y=y5; ob.z=y6; ob.w=y7;
    float* op = (float*)out + (size_t)row * DIM + lane * 8;
    *(float4*)op = oa;
    *(float4*)(op + 4) = ob;
  }
}

// ---------------- MFMA GEMM (best config: R3 core, KU=2, XCD swizzle) ---------
// C[M,N] = A[M,K] * Bt[N,K]^T. BM=BN=128, 256 thr (2x2 waves, 4x4 frags).
// KU=2: stage 2x64-K chunks, one vmcnt-drain pair per 128-K (64KB LDS).
// MODE 0: bf16 = acc+bias; 1: bf16 gelu(acc+bias);
// MODE 2: bf16 h += acc+bias (RMW); 3: bf16 h[b,1+p]=acc+bias+pos (patch-embed)
template<int MODE, int KU>
__global__ __launch_bounds__(256) void k_gemm(
    const short* __restrict__ A, const short* __restrict__ Bt,
    const float* __restrict__ bias, void* __restrict__ out,
    const float* __restrict__ extra, int M, int N, int K)
{
  __shared__ short As[KU][128 * 64];
  __shared__ short Bs[KU][128 * 64];
  // bijective XCD swizzle (m204): same-bm blocks cluster on one XCD's L2
  int gx = gridDim.x;
  int nwg = gx * gridDim.y;
  int orig = blockIdx.y * gx + blockIdx.x;
  int q = nwg >> 3, r = nwg & 7, xcd = orig & 7, off = orig >> 3;
  int nid = (xcd < r ? xcd * (q + 1) : r * (q + 1) + (xcd - r) * q) + off;
  int bm = nid / gx, bn = nid % gx;

  int t = threadIdx.x, wid = t >> 6, lane = t & 63;
  int wm = wid >> 1, wn = wid & 1;
  int lr = lane & 15, lk = lane >> 4;
  int srow = lane >> 3;            // 0..7
  int scol = (lane & 7) * 8;       // shorts
  vf4 acc[4][4];
  #pragma unroll
  for (int i = 0; i < 4; ++i)
    #pragma unroll
    for (int j = 0; j < 4; ++j) {
      acc[i][j][0] = 0.f; acc[i][j][1] = 0.f; acc[i][j][2] = 0.f; acc[i][j][3] = 0.f;
    }

  const short* Abase = A  + (size_t)(bm * 128 + srow) * K + scol;
  const short* Bbase = Bt + (size_t)(bn * 128 + srow) * K + scol;

  for (int k0 = 0; k0 < K; k0 += KU * 64) {
    if (k0) __syncthreads();
    #pragma unroll
    for (int u = 0; u < KU; ++u) {
      #pragma unroll
      for (int i = 0; i < 4; ++i) {
        int rc = wid * 4 + i;                     // 8-row chunk id (0..15)
        gl_lds16(Abase + (size_t)(rc * 8) * K + k0 + u * 64, &As[u][rc * 512]);
        gl_lds16(Bbase + (size_t)(rc * 8) * K + k0 + u * 64, &Bs[u][rc * 512]);
      }
    }
    __syncthreads();                              // single vmcnt drain per KU*64
    #pragma unroll
    for (int u = 0; u < KU; ++u) {
      #pragma unroll
      for (int s = 0; s < 2; ++s) {
        vbf8 af[4], bfr[4];
        #pragma unroll
        for (int i = 0; i < 4; ++i)
          af[i] = *(const vbf8*)&As[u][(wm * 64 + i * 16 + lr) * 64 + s * 32 + lk * 8];
        #pragma unroll
        for (int j = 0; j < 4; ++j)
          bfr[j] = *(const vbf8*)&Bs[u][(wn * 64 + j * 16 + lr) * 64 + s * 32 + lk * 8];
        #pragma unroll
        for (int i = 0; i < 4; ++i)
          #pragma unroll
          for (int j = 0; j < 4; ++j)
            acc[i][j] = __builtin_amdgcn_mfma_f32_16x16x32_bf16(af[i], bfr[j], acc[i][j], 0, 0, 0);
      }
    }
  }

  int rbase = bm * 128 + wm * 64;
  int cbase = bn * 128 + wn * 64;
  #pragma unroll
  for (int i = 0; i < 4; ++i) {
    #pragma unroll
    for (int j = 0; j < 4; ++j) {
      int col = cbase + j * 16 + lr;
      float bs = bias[col];
      #pragma unroll
      for (int z = 0; z < 4; ++z) {
        int row = rbase + i * 16 + lk * 4 + z;
        if (row < M) {
          float v = acc[i][j][z] + bs;
          if (MODE == 0) {
            ((short*)out)[(size_t)row * N + col] = f2bf(v);
          } else if (MODE == 1) {
            float g = 0.5f * v * (1.f + erff(v * 0.70710678118f));
            ((short*)out)[(size_t)row * N + col] = f2bf(g);
          } else if (MODE == 2) {
            short* hp = (short*)out + (size_t)row * N + col;
            *hp = f2bf(bf2f(*hp) + v);
          } else {
            ((short*)out)[((size_t)(row / NPATCH) * NTOK + 1 + (row % NPATCH)) * DIM + col] =
                f2bf(v + extra[(size_t)(1 + (row % NPATCH)) * DIM + col]);
          }
        }
      }
    }
  }
}

// ---------------- MFMA flash attention: block per (batch, head) ---------------
// S^T = K*Q^T (swapped operands), softmax in-register, P staged per-wave in LDS,
// V^T staged per-block (XOR-swizzled), O^T = V^T*P^T.
#define VSTR 232   // shorts per Vt/Pt row (224 cols + pad; stride 16B-aligned)
__global__ __launch_bounds__(256) void k_attn(const short* __restrict__ qkv,
                                              short* __restrict__ o) {
  int h = blockIdx.x, b = blockIdx.y;
  __shared__ short Vt[64 * VSTR];          // V^T [dv 64][k 224], col ^ ((dv>>3)&3)<<3
  __shared__ short Pt[4][16 * VSTR];       // per-wave P [q 16][k 224]
  int t = threadIdx.x, wid = t >> 6, lane = t & 63;
  int lq = lane & 15, g4 = lane >> 4;
  const size_t base = (size_t)(b * NTOK) * 1536 + h * 64;

  // stage V^T (zero cols >= 197)
  vbf8 vz;
  #pragma unroll
  for (int j = 0; j < 8; ++j) vz[j] = 0;
  for (int idx = t; idx < 224 * 8; idx += 256) {
    int r = idx >> 3, c8 = idx & 7;
    vbf8 v = vz;
    if (r < NTOK) v = *(const vbf8*)(qkv + base + (size_t)r * 1536 + 1024 + c8 * 8);
    int cs = r ^ ((c8 & 3) << 3);
    #pragma unroll
    for (int j = 0; j < 8; ++j) Vt[(c8 * 8 + j) * VSTR + cs] = v[j];
  }
  __syncthreads();

  short* Pw = &Pt[wid][0];
  for (int qt = wid; qt < 13; qt += 4) {
    const short* qp = qkv + base + (size_t)(qt * 16 + lq) * 1536 + g4 * 8;
    vbf8 qf0 = *(const vbf8*)qp;
    vbf8 qf1 = *(const vbf8*)(qp + 32);
    float sc[13][4];
    #pragma unroll
    for (int kt = 0; kt < 13; ++kt) {
      const short* kp = qkv + base + (size_t)(kt * 16 + lq) * 1536 + 512 + g4 * 8;
      vbf8 kf0 = *(const vbf8*)kp;
      vbf8 kf1 = *(const vbf8*)(kp + 32);
      vf4 s; s[0] = 0.f; s[1] = 0.f; s[2] = 0.f; s[3] = 0.f;
      s = __builtin_amdgcn_mfma_f32_16x16x32_bf16(kf0, qf0, s, 0, 0, 0);
      s = __builtin_amdgcn_mfma_f32_16x16x32_bf16(kf1, qf1, s, 0, 0, 0);
      #pragma unroll
      for (int z = 0; z < 4; ++z) {
        int krow = kt * 16 + g4 * 4 + z;
        sc[kt][z] = (krow < NTOK) ? s[z] * 0.125f : -1e30f;
      }
    }
    float mx = -1e30f;
    #pragma unroll
    for (int kt = 0; kt < 13; ++kt)
      #pragma unroll
      for (int z = 0; z < 4; ++z) mx = fmaxf(mx, sc[kt][z]);
    mx = fmaxf(mx, __shfl_xor(mx, 16));
    mx = fmaxf(mx, __shfl_xor(mx, 32));
    float sum = 0.f;
    #pragma unroll
    for (int kt = 0; kt < 13; ++kt)
      #pragma unroll
      for (int z = 0; z < 4; ++z) {
        float e = __expf(sc[kt][z] - mx);
        sc[kt][z] = e;
        sum += e;
      }
    sum += __shfl_xor(sum, 16);
    sum += __shfl_xor(sum, 32);
    float inv = 1.f / sum;
    #pragma unroll
    for (int kt = 0; kt < 13; ++kt) {
      *(short4*)&Pw[lq * VSTR + kt * 16 + g4 * 4] =
          make_short4(f2bf(sc[kt][0]), f2bf(sc[kt][1]), f2bf(sc[kt][2]), f2bf(sc[kt][3]));
    }
    *(short4*)&Pw[lq * VSTR + 208 + g4 * 4] = make_short4(0, 0, 0, 0); // k 208..223
    vf4 oacc[4];
    #pragma unroll
    for (int dt = 0; dt < 4; ++dt) { oacc[dt][0]=0.f; oacc[dt][1]=0.f; oacc[dt][2]=0.f; oacc[dt][3]=0.f; }
    #pragma unroll
    for (int u = 0; u < 7; ++u) {
      vbf8 pb = *(const vbf8*)&Pw[lq * VSTR + u * 32 + g4 * 8];
      #pragma unroll
      for (int dt = 0; dt < 4; ++dt) {
        int swz = ((dt * 2 + (lq >> 3)) & 3) << 3;
        vbf8 va = *(const vbf8*)&Vt[(dt * 16 + lq) * VSTR + ((u * 32 + g4 * 8) ^ swz)];
        oacc[dt] = __builtin_amdgcn_mfma_f32_16x16x32_bf16(va, pb, oacc[dt], 0, 0, 0);
      }
    }
    int qrow = qt * 16 + lq;
    if (qrow < NTOK) {
      short* op = o + ((size_t)(b * NTOK) + qrow) * DIM + h * 64 + g4 * 4;
      #pragma unroll
      for (int dt = 0; dt < 4; ++dt)
        *(short4*)(op + dt * 16) = make_short4(f2bf(oacc[dt][0] * inv), f2bf(oacc[dt][1] * inv),
                                               f2bf(oacc[dt][2] * inv), f2bf(oacc[dt][3] * inv));
    }
  }
}

// ------------------------------- launch ---------------------------------------
extern "C" void kernel_launch(void* const* d_in, const int* in_sizes, int n_in,
                              void* d_out, int out_size, void* d_ws, size_t ws_size,
                              hipStream_t stream) {
  (void)in_sizes; (void)n_in; (void)out_size; (void)ws_size;
  const float* x      = (const float*)d_in[0];
  const float* conv_w = (const float*)d_in[1];
  const float* conv_b = (const float*)d_in[2];
  const float* cls    = (const float*)d_in[3];
  const float* pos    = (const float*)d_in[4];
  const float* ln1_w  = (const float*)d_in[5];
  const float* ln1_b  = (const float*)d_in[6];
  const float* qkv_w  = (const float*)d_in[7];
  const float* qkv_b  = (const float*)d_in[8];
  const float* proj_w = (const float*)d_in[9];
  const float* proj_b = (const float*)d_in[10];
  const float* ln2_w  = (const float*)d_in[11];
  const float* ln2_b  = (const float*)d_in[12];
  const float* fc1_w  = (const float*)d_in[13];
  const float* fc1_b  = (const float*)d_in[14];
  const float* fc2_w  = (const float*)d_in[15];
  const float* fc2_b  = (const float*)d_in[16];
  const float* norm_w = (const float*)d_in[17];
  const float* norm_b = (const float*)d_in[18];

  short* conv_wT = (short*)d_ws;                       // [512][768]
  short* qkv_wT  = conv_wT + (size_t)512 * 768;        // 4x[1536][512]
  short* proj_wT = qkv_wT  + (size_t)4 * 1536 * 512;   // 4x[512][512]
  short* fc1_wT  = proj_wT + (size_t)4 * 512 * 512;    // 4x[1024][512]
  short* fc2_wT  = fc1_wT  + (size_t)4 * 512 * 1024;   // 4x[512][1024]
  short* y_bf    = fc2_wT  + (size_t)4 * 1024 * 512;   // [12608][512]
  short* o_bf    = y_bf    + (size_t)MTOK * 512;       // [12608][512]
  short* big     = o_bf    + (size_t)MTOK * 512;       // patches / qkv / mlp alias
  short* h       = big     + (size_t)MTOK * 1536;      // [12608][512] bf16 residual

  k_cvt_t<<<dim3(8, 12, 1), 256, 0, stream>>>(conv_w, conv_wT, 768, 512);
  k_cvt_t<<<dim3(24, 8, 4), 256, 0, stream>>>(qkv_w, qkv_wT, 512, 1536);
  k_cvt_t<<<dim3(8, 8, 4), 256, 0, stream>>>(proj_w, proj_wT, 512, 512);
  k_cvt_t<<<dim3(16, 8, 4), 256, 0, stream>>>(fc1_w, fc1_wT, 512, 1024);
  k_cvt_t<<<dim3(8, 16, 4), 256, 0, stream>>>(fc2_w, fc2_wT, 1024, 512);

  k_im2col<<<2352, 256, 0, stream>>>(x, big);
  k_cls<<<64, 256, 0, stream>>>(cls, pos, h);
  k_gemm<3, 2><<<dim3(4, 98), 256, 0, stream>>>(big, conv_wT, conv_b, h, pos,
                                                MPATCH, 512, 768);
  for (int i = 0; i < 4; ++i) {
    k_ln<1><<<MTOK / 4, 256, 0, stream>>>(h, ln1_w + i * 512, ln1_b + i * 512, y_bf);
    k_gemm<0, 2><<<dim3(12, 99), 256, 0, stream>>>(y_bf, qkv_wT + (size_t)i * 512 * 1536,
                                                   qkv_b + i * 1536, big, nullptr,
                                                   MTOK, 1536, 512);
    k_attn<<<dim3(8, 64), 256, 0, stream>>>(big, o_bf);
    k_gemm<2, 2><<<dim3(4, 99), 256, 0, stream>>>(o_bf, proj_wT + (size_t)i * 512 * 512,
                                                  proj_b + i * 512, h, nullptr,
                                                  MTOK, 512, 512);
    k_ln<1><<<MTOK / 4, 256, 0, stream>>>(h, ln2_w + i * 512, ln2_b + i * 512, y_bf);
    k_gemm<1, 2><<<dim3(8, 99), 256, 0, stream>>>(y_bf, fc1_wT + (size_t)i * 512 * 1024,
                                                  fc1_b + i * 1024, big, nullptr,
                                                  MTOK, 1024, 512);
    k_gemm<2, 2><<<dim3(4, 99), 256, 0, stream>>>(big, fc2_wT + (size_t)i * 1024 * 512,
                                                  fc2_b + i * 512, h, nullptr,
                                                  MTOK, 512, 1024);
  }
  k_ln<0><<<MTOK / 4, 256, 0, stream>>>(h, norm_w, norm_b, d_out);
}

// Round 17
// 847.214 us; speedup vs baseline: 1.1828x; 1.0119x over previous
//
#include <hip/hip_runtime.h>
#include <hip/hip_bf16.h>

#define HEADS 8
#define DIM 512
#define HID 1024
#define NTOK 197
#define NPATCH 196
#define BATCH 64
#define MTOK (BATCH*NTOK)     // 12608
#define MPATCH (BATCH*NPATCH) // 12544
#define KPATCH 768

typedef __attribute__((ext_vector_type(8))) short vbf8;
typedef __attribute__((ext_vector_type(4))) float vf4;

__device__ inline float bf2f(short u) {
  union { unsigned int i; float f; } v; v.i = ((unsigned int)(unsigned short)u) << 16; return v.f;
}
__device__ inline short f2bf(float f) {
  union { float f; unsigned int i; } u; u.f = f;
  unsigned int r = u.i + 0x7fffu + ((u.i >> 16) & 1u);
  return (short)(r >> 16);
}

__device__ inline void gl_lds16(const void* g, void* l) {
  __builtin_amdgcn_global_load_lds(
      (const __attribute__((address_space(1))) void*)g,
      (__attribute__((address_space(3))) void*)l, 16, 0, 0);
}

// ---------------- ALL weight converts in ONE dispatch --------------------------
// in[K][N] f32 -> out[N][K] bf16, 64x64 tiles, flat blockIdx decode:
// [0,96) conv | [96,864) qkv x4 | [864,1120) proj x4 | [1120,1632) fc1 x4
// [1632,2144) fc2 x4.  Arithmetic per element identical to the old k_cvt_t.
__global__ void k_cvt_all(const float* __restrict__ cw, const float* __restrict__ qw,
                          const float* __restrict__ pw, const float* __restrict__ f1,
                          const float* __restrict__ f2,
                          short* cwT, short* qwT, short* pwT, short* f1T, short* f2T) {
  int i = blockIdx.x;
  const float* in; short* out; int K, N, tx, ty;
  if (i < 96)        { in = cw; out = cwT; K = 768; N = 512; tx = i % 8; ty = i / 8; }
  else if (i < 864)  { int j = i - 96, s = j / 192, r = j % 192; K = 512; N = 1536;
                       in = qw + (size_t)s * K * N; out = qwT + (size_t)s * K * N;
                       tx = r % 24; ty = r / 24; }
  else if (i < 1120) { int j = i - 864, s = j / 64, r = j % 64; K = 512; N = 512;
                       in = pw + (size_t)s * K * N; out = pwT + (size_t)s * K * N;
                       tx = r % 8; ty = r / 8; }
  else if (i < 1632) { int j = i - 1120, s = j / 128, r = j % 128; K = 512; N = 1024;
                       in = f1 + (size_t)s * K * N; out = f1T + (size_t)s * K * N;
                       tx = r % 16; ty = r / 16; }
  else               { int j = i - 1632, s = j / 128, r = j % 128; K = 1024; N = 512;
                       in = f2 + (size_t)s * K * N; out = f2T + (size_t)s * K * N;
                       tx = r % 8; ty = r / 8; }
  __shared__ short tile[64][72];
  int t = threadIdx.x;
  int k0 = ty * 64, n0 = tx * 64;
  int r = t >> 2, c4 = (t & 3) << 4;
  #pragma unroll
  for (int j = 0; j < 16; j += 4) {
    float4 v = *(const float4*)(in + (size_t)(k0 + r) * N + n0 + c4 + j);
    tile[r][c4 + j + 0] = f2bf(v.x);
    tile[r][c4 + j + 1] = f2bf(v.y);
    tile[r][c4 + j + 2] = f2bf(v.z);
    tile[r][c4 + j + 3] = f2bf(v.w);
  }
  __syncthreads();
  int n = t >> 2, kc = (t & 3) << 4;
  vbf8 a, b;
  #pragma unroll
  for (int j = 0; j < 8; ++j) a[j] = tile[kc + j][n];
  #pragma unroll
  for (int j = 0; j < 8; ++j) b[j] = tile[kc + 8 + j][n];
  *(vbf8*)(out + (size_t)(n0 + n) * K + k0 + kc) = a;
  *(vbf8*)(out + (size_t)(n0 + n) * K + k0 + kc + 8) = b;
}

// ---------------- im2col: x[B,3,224,224] f32 -> patches[12544, 768] bf16 -------
__global__ void k_im2col(const float* __restrict__ x, short* __restrict__ patches) {
  int tid = blockIdx.x * 256 + threadIdx.x;
  if (tid >= MPATCH * 48) return;
  int b = tid / (NPATCH * 48);
  int r = tid % (NPATCH * 48);
  int p = r / 48;
  int ck = r % 48;
  int c = ck >> 4, kh = ck & 15;
  int gy = p / 14, gx = p % 14;
  const float* src = x + ((size_t)((b * 3 + c) * 224) + gy * 16 + kh) * 224 + gx * 16;
  short* dst = patches + (size_t)(b * NPATCH + p) * KPATCH + c * 256 + kh * 16;
  float4 v0 = *(const float4*)(src);
  float4 v1 = *(const float4*)(src + 4);
  float4 v2 = *(const float4*)(src + 8);
  float4 v3 = *(const float4*)(src + 12);
  vbf8 o0, o1;
  o0[0]=f2bf(v0.x); o0[1]=f2bf(v0.y); o0[2]=f2bf(v0.z); o0[3]=f2bf(v0.w);
  o0[4]=f2bf(v1.x); o0[5]=f2bf(v1.y); o0[6]=f2bf(v1.z); o0[7]=f2bf(v1.w);
  o1[0]=f2bf(v2.x); o1[1]=f2bf(v2.y); o1[2]=f2bf(v2.z); o1[3]=f2bf(v2.w);
  o1[4]=f2bf(v3.x); o1[5]=f2bf(v3.y); o1[6]=f2bf(v3.z); o1[7]=f2bf(v3.w);
  *(vbf8*)dst = o0;
  *(vbf8*)(dst + 8) = o1;
}

// ---------------- cls token init (bf16 residual) -------------------------------
__global__ void k_cls(const float* __restrict__ cls, const float* __restrict__ pos,
                      short* __restrict__ h) {
  int b = blockIdx.x, t = threadIdx.x;
  short* hr = h + (size_t)b * NTOK * DIM;
  hr[t]       = f2bf(cls[t]       + pos[t]);
  hr[t + 256] = f2bf(cls[t + 256] + pos[t + 256]);
}

// ---------------- LayerNorm over DIM=512 (bf16 in): wave/row, 4 rows/block ----
template<int OUTBF>
__global__ __launch_bounds__(256) void k_ln(const short* __restrict__ x,
                                            const float* __restrict__ w,
                                            const float* __restrict__ b,
                                            void* __restrict__ out) {
  int wid = threadIdx.x >> 6, lane = threadIdx.x & 63;
  int row = blockIdx.x * 4 + wid;
  vbf8 xv = *(const vbf8*)(x + (size_t)row * DIM + lane * 8);
  float v0 = bf2f(xv[0]), v1 = bf2f(xv[1]), v2 = bf2f(xv[2]), v3 = bf2f(xv[3]);
  float v4 = bf2f(xv[4]), v5 = bf2f(xv[5]), v6 = bf2f(xv[6]), v7 = bf2f(xv[7]);
  float s  = v0 + v1 + v2 + v3 + v4 + v5 + v6 + v7;
  float ss = v0*v0 + v1*v1 + v2*v2 + v3*v3 + v4*v4 + v5*v5 + v6*v6 + v7*v7;
  #pragma unroll
  for (int o = 32; o > 0; o >>= 1) { s += __shfl_xor(s, o); ss += __shfl_xor(ss, o); }
  float mu = s * (1.0f / DIM);
  float var = ss * (1.0f / DIM) - mu * mu;
  float rs = rsqrtf(var + 1e-5f);
  float4 wa = *(const float4*)(w + lane * 8);
  float4 wb = *(const float4*)(w + lane * 8 + 4);
  float4 ba = *(const float4*)(b + lane * 8);
  float4 bb = *(const float4*)(b + lane * 8 + 4);
  float y0 = (v0 - mu) * rs * wa.x + ba.x;
  float y1 = (v1 - mu) * rs * wa.y + ba.y;
  float y2 = (v2 - mu) * rs * wa.z + ba.z;
  float y3 = (v3 - mu) * rs * wa.w + ba.w;
  float y4 = (v4 - mu) * rs * wb.x + bb.x;
  float y5 = (v5 - mu) * rs * wb.y + bb.y;
  float y6 = (v6 - mu) * rs * wb.z + bb.z;
  float y7 = (v7 - mu) * rs * wb.w + bb.w;
  if (OUTBF) {
    vbf8 pk;
    pk[0]=f2bf(y0); pk[1]=f2bf(y1); pk[2]=f2bf(y2); pk[3]=f2bf(y3);
    pk[4]=f2bf(y4); pk[5]=f2bf(y5); pk[6]=f2bf(y6); pk[7]=f2bf(y7);
    *(vbf8*)((short*)out + (size_t)row * DIM + lane * 8) = pk;
  } else {
    float4 oa, ob;
    oa.x=y0; oa.y=y1; oa.z=y2; oa.w=y3;
    ob.x=y4; ob.y=y5; ob.z=y6; ob.w=y7;
    float* op = (float*)out + (size_t)row * DIM + lane * 8;
    *(float4*)op = oa;
    *(float4*)(op + 4) = ob;
  }
}

// ---------------- MFMA GEMM (best config: R3 core, KU=2, XCD swizzle) ---------
// C[M,N] = A[M,K] * Bt[N,K]^T. BM=BN=128, 256 thr (2x2 waves, 4x4 frags).
// KU=2: stage 2x64-K chunks, one vmcnt-drain pair per 128-K (64KB LDS).
// MODE 0: bf16 = acc+bias; 1: bf16 gelu(acc+bias);
// MODE 2: bf16 h += acc+bias (RMW); 3: bf16 h[b,1+p]=acc+bias+pos (patch-embed)
template<int MODE, int KU>
__global__ __launch_bounds__(256) void k_gemm(
    const short* __restrict__ A, const short* __restrict__ Bt,
    const float* __restrict__ bias, void* __restrict__ out,
    const float* __restrict__ extra, int M, int N, int K)
{
  __shared__ short As[KU][128 * 64];
  __shared__ short Bs[KU][128 * 64];
  // bijective XCD swizzle (m204): same-bm blocks cluster on one XCD's L2
  int gx = gridDim.x;
  int nwg = gx * gridDim.y;
  int orig = blockIdx.y * gx + blockIdx.x;
  int q = nwg >> 3, r = nwg & 7, xcd = orig & 7, off = orig >> 3;
  int nid = (xcd < r ? xcd * (q + 1) : r * (q + 1) + (xcd - r) * q) + off;
  int bm = nid / gx, bn = nid % gx;

  int t = threadIdx.x, wid = t >> 6, lane = t & 63;
  int wm = wid >> 1, wn = wid & 1;
  int lr = lane & 15, lk = lane >> 4;
  int srow = lane >> 3;            // 0..7
  int scol = (lane & 7) * 8;       // shorts
  vf4 acc[4][4];
  #pragma unroll
  for (int i = 0; i < 4; ++i)
    #pragma unroll
    for (int j = 0; j < 4; ++j) {
      acc[i][j][0] = 0.f; acc[i][j][1] = 0.f; acc[i][j][2] = 0.f; acc[i][j][3] = 0.f;
    }

  const short* Abase = A  + (size_t)(bm * 128 + srow) * K + scol;
  const short* Bbase = Bt + (size_t)(bn * 128 + srow) * K + scol;

  for (int k0 = 0; k0 < K; k0 += KU * 64) {
    if (k0) __syncthreads();
    #pragma unroll
    for (int u = 0; u < KU; ++u) {
      #pragma unroll
      for (int i = 0; i < 4; ++i) {
        int rc = wid * 4 + i;                     // 8-row chunk id (0..15)
        gl_lds16(Abase + (size_t)(rc * 8) * K + k0 + u * 64, &As[u][rc * 512]);
        gl_lds16(Bbase + (size_t)(rc * 8) * K + k0 + u * 64, &Bs[u][rc * 512]);
      }
    }
    __syncthreads();                              // single vmcnt drain per KU*64
    #pragma unroll
    for (int u = 0; u < KU; ++u) {
      #pragma unroll
      for (int s = 0; s < 2; ++s) {
        vbf8 af[4], bfr[4];
        #pragma unroll
        for (int i = 0; i < 4; ++i)
          af[i] = *(const vbf8*)&As[u][(wm * 64 + i * 16 + lr) * 64 + s * 32 + lk * 8];
        #pragma unroll
        for (int j = 0; j < 4; ++j)
          bfr[j] = *(const vbf8*)&Bs[u][(wn * 64 + j * 16 + lr) * 64 + s * 32 + lk * 8];
        #pragma unroll
        for (int i = 0; i < 4; ++i)
          #pragma unroll
          for (int j = 0; j < 4; ++j)
            acc[i][j] = __builtin_amdgcn_mfma_f32_16x16x32_bf16(af[i], bfr[j], acc[i][j], 0, 0, 0);
      }
    }
  }

  int rbase = bm * 128 + wm * 64;
  int cbase = bn * 128 + wn * 64;
  #pragma unroll
  for (int i = 0; i < 4; ++i) {
    #pragma unroll
    for (int j = 0; j < 4; ++j) {
      int col = cbase + j * 16 + lr;
      float bs = bias[col];
      #pragma unroll
      for (int z = 0; z < 4; ++z) {
        int row = rbase + i * 16 + lk * 4 + z;
        if (row < M) {
          float v = acc[i][j][z] + bs;
          if (MODE == 0) {
            ((short*)out)[(size_t)row * N + col] = f2bf(v);
          } else if (MODE == 1) {
            float g = 0.5f * v * (1.f + erff(v * 0.70710678118f));
            ((short*)out)[(size_t)row * N + col] = f2bf(g);
          } else if (MODE == 2) {
            short* hp = (short*)out + (size_t)row * N + col;
            *hp = f2bf(bf2f(*hp) + v);
          } else {
            ((short*)out)[((size_t)(row / NPATCH) * NTOK + 1 + (row % NPATCH)) * DIM + col] =
                f2bf(v + extra[(size_t)(1 + (row % NPATCH)) * DIM + col]);
          }
        }
      }
    }
  }
}

// ---------------- MFMA flash attention: block per (batch, head) ---------------
// S^T = K*Q^T (swapped operands), softmax in-register, P staged per-wave in LDS,
// V^T staged per-block (XOR-swizzled), O^T = V^T*P^T.
#define VSTR 232   // shorts per Vt/Pt row (224 cols + pad; stride 16B-aligned)
__global__ __launch_bounds__(256) void k_attn(const short* __restrict__ qkv,
                                              short* __restrict__ o) {
  int h = blockIdx.x, b = blockIdx.y;
  __shared__ short Vt[64 * VSTR];          // V^T [dv 64][k 224], col ^ ((dv>>3)&3)<<3
  __shared__ short Pt[4][16 * VSTR];       // per-wave P [q 16][k 224]
  int t = threadIdx.x, wid = t >> 6, lane = t & 63;
  int lq = lane & 15, g4 = lane >> 4;
  const size_t base = (size_t)(b * NTOK) * 1536 + h * 64;

  // stage V^T (zero cols >= 197)
  vbf8 vz;
  #pragma unroll
  for (int j = 0; j < 8; ++j) vz[j] = 0;
  for (int idx = t; idx < 224 * 8; idx += 256) {
    int r = idx >> 3, c8 = idx & 7;
    vbf8 v = vz;
    if (r < NTOK) v = *(const vbf8*)(qkv + base + (size_t)r * 1536 + 1024 + c8 * 8);
    int cs = r ^ ((c8 & 3) << 3);
    #pragma unroll
    for (int j = 0; j < 8; ++j) Vt[(c8 * 8 + j) * VSTR + cs] = v[j];
  }
  __syncthreads();

  short* Pw = &Pt[wid][0];
  for (int qt = wid; qt < 13; qt += 4) {
    const short* qp = qkv + base + (size_t)(qt * 16 + lq) * 1536 + g4 * 8;
    vbf8 qf0 = *(const vbf8*)qp;
    vbf8 qf1 = *(const vbf8*)(qp + 32);
    float sc[13][4];
    #pragma unroll
    for (int kt = 0; kt < 13; ++kt) {
      const short* kp = qkv + base + (size_t)(kt * 16 + lq) * 1536 + 512 + g4 * 8;
      vbf8 kf0 = *(const vbf8*)kp;
      vbf8 kf1 = *(const vbf8*)(kp + 32);
      vf4 s; s[0] = 0.f; s[1] = 0.f; s[2] = 0.f; s[3] = 0.f;
      s = __builtin_amdgcn_mfma_f32_16x16x32_bf16(kf0, qf0, s, 0, 0, 0);
      s = __builtin_amdgcn_mfma_f32_16x16x32_bf16(kf1, qf1, s, 0, 0, 0);
      #pragma unroll
      for (int z = 0; z < 4; ++z) {
        int krow = kt * 16 + g4 * 4 + z;
        sc[kt][z] = (krow < NTOK) ? s[z] * 0.125f : -1e30f;
      }
    }
    float mx = -1e30f;
    #pragma unroll
    for (int kt = 0; kt < 13; ++kt)
      #pragma unroll
      for (int z = 0; z < 4; ++z) mx = fmaxf(mx, sc[kt][z]);
    mx = fmaxf(mx, __shfl_xor(mx, 16));
    mx = fmaxf(mx, __shfl_xor(mx, 32));
    float sum = 0.f;
    #pragma unroll
    for (int kt = 0; kt < 13; ++kt)
      #pragma unroll
      for (int z = 0; z < 4; ++z) {
        float e = __expf(sc[kt][z] - mx);
        sc[kt][z] = e;
        sum += e;
      }
    sum += __shfl_xor(sum, 16);
    sum += __shfl_xor(sum, 32);
    float inv = 1.f / sum;
    #pragma unroll
    for (int kt = 0; kt < 13; ++kt) {
      *(short4*)&Pw[lq * VSTR + kt * 16 + g4 * 4] =
          make_short4(f2bf(sc[kt][0]), f2bf(sc[kt][1]), f2bf(sc[kt][2]), f2bf(sc[kt][3]));
    }
    *(short4*)&Pw[lq * VSTR + 208 + g4 * 4] = make_short4(0, 0, 0, 0); // k 208..223
    vf4 oacc[4];
    #pragma unroll
    for (int dt = 0; dt < 4; ++dt) { oacc[dt][0]=0.f; oacc[dt][1]=0.f; oacc[dt][2]=0.f; oacc[dt][3]=0.f; }
    #pragma unroll
    for (int u = 0; u < 7; ++u) {
      vbf8 pb = *(const vbf8*)&Pw[lq * VSTR + u * 32 + g4 * 8];
      #pragma unroll
      for (int dt = 0; dt < 4; ++dt) {
        int swz = ((dt * 2 + (lq >> 3)) & 3) << 3;
        vbf8 va = *(const vbf8*)&Vt[(dt * 16 + lq) * VSTR + ((u * 32 + g4 * 8) ^ swz)];
        oacc[dt] = __builtin_amdgcn_mfma_f32_16x16x32_bf16(va, pb, oacc[dt], 0, 0, 0);
      }
    }
    int qrow = qt * 16 + lq;
    if (qrow < NTOK) {
      short* op = o + ((size_t)(b * NTOK) + qrow) * DIM + h * 64 + g4 * 4;
      #pragma unroll
      for (int dt = 0; dt < 4; ++dt)
        *(short4*)(op + dt * 16) = make_short4(f2bf(oacc[dt][0] * inv), f2bf(oacc[dt][1] * inv),
                                               f2bf(oacc[dt][2] * inv), f2bf(oacc[dt][3] * inv));
    }
  }
}

// ------------------------------- launch ---------------------------------------
extern "C" void kernel_launch(void* const* d_in, const int* in_sizes, int n_in,
                              void* d_out, int out_size, void* d_ws, size_t ws_size,
                              hipStream_t stream) {
  (void)in_sizes; (void)n_in; (void)out_size; (void)ws_size;
  const float* x      = (const float*)d_in[0];
  const float* conv_w = (const float*)d_in[1];
  const float* conv_b = (const float*)d_in[2];
  const float* cls    = (const float*)d_in[3];
  const float* pos    = (const float*)d_in[4];
  const float* ln1_w  = (const float*)d_in[5];
  const float* ln1_b  = (const float*)d_in[6];
  const float* qkv_w  = (const float*)d_in[7];
  const float* qkv_b  = (const float*)d_in[8];
  const float* proj_w = (const float*)d_in[9];
  const float* proj_b = (const float*)d_in[10];
  const float* ln2_w  = (const float*)d_in[11];
  const float* ln2_b  = (const float*)d_in[12];
  const float* fc1_w  = (const float*)d_in[13];
  const float* fc1_b  = (const float*)d_in[14];
  const float* fc2_w  = (const float*)d_in[15];
  const float* fc2_b  = (const float*)d_in[16];
  const float* norm_w = (const float*)d_in[17];
  const float* norm_b = (const float*)d_in[18];

  short* conv_wT = (short*)d_ws;                       // [512][768]
  short* qkv_wT  = conv_wT + (size_t)512 * 768;        // 4x[1536][512]
  short* proj_wT = qkv_wT  + (size_t)4 * 1536 * 512;   // 4x[512][512]
  short* fc1_wT  = proj_wT + (size_t)4 * 512 * 512;    // 4x[1024][512]
  short* fc2_wT  = fc1_wT  + (size_t)4 * 512 * 1024;   // 4x[512][1024]
  short* y_bf    = fc2_wT  + (size_t)4 * 1024 * 512;   // [12608][512]
  short* o_bf    = y_bf    + (size_t)MTOK * 512;       // [12608][512]
  short* big     = o_bf    + (size_t)MTOK * 512;       // patches / qkv / mlp alias
  short* h       = big     + (size_t)MTOK * 1536;      // [12608][512] bf16 residual

  k_cvt_all<<<2144, 256, 0, stream>>>(conv_w, qkv_w, proj_w, fc1_w, fc2_w,
                                      conv_wT, qkv_wT, proj_wT, fc1_wT, fc2_wT);

  k_im2col<<<2352, 256, 0, stream>>>(x, big);
  k_cls<<<64, 256, 0, stream>>>(cls, pos, h);
  k_gemm<3, 2><<<dim3(4, 98), 256, 0, stream>>>(big, conv_wT, conv_b, h, pos,
                                                MPATCH, 512, 768);
  for (int i = 0; i < 4; ++i) {
    k_ln<1><<<MTOK / 4, 256, 0, stream>>>(h, ln1_w + i * 512, ln1_b + i * 512, y_bf);
    k_gemm<0, 2><<<dim3(12, 99), 256, 0, stream>>>(y_bf, qkv_wT + (size_t)i * 512 * 1536,
                                                   qkv_b + i * 1536, big, nullptr,
                                                   MTOK, 1536, 512);
    k_attn<<<dim3(8, 64), 256, 0, stream>>>(big, o_bf);
    k_gemm<2, 2><<<dim3(4, 99), 256, 0, stream>>>(o_bf, proj_wT + (size_t)i * 512 * 512,
                                                  proj_b + i * 512, h, nullptr,
                                                  MTOK, 512, 512);
    k_ln<1><<<MTOK / 4, 256, 0, stream>>>(h, ln2_w + i * 512, ln2_b + i * 512, y_bf);
    k_gemm<1, 2><<<dim3(8, 99), 256, 0, stream>>>(y_bf, fc1_wT + (size_t)i * 512 * 1024,
                                                  fc1_b + i * 1024, big, nullptr,
                                                  MTOK, 1024, 512);
    k_gemm<2, 2><<<dim3(4, 99), 256, 0, stream>>>(big, fc2_wT + (size_t)i * 1024 * 512,
                                                  fc2_b + i * 512, h, nullptr,
                                                  MTOK, 512, 1024);
  }
  k_ln<0><<<MTOK / 4, 256, 0, stream>>>(h, norm_w, norm_b, d_out);
}